// Round 1
// baseline (273.084 us; speedup 1.0000x reference)
//
#include <hip/hip_runtime.h>
#include <hip/hip_bf16.h>

typedef short short8 __attribute__((ext_vector_type(8)));
typedef float f32x4 __attribute__((ext_vector_type(4)));

#define MFMA32(a, b, c) __builtin_amdgcn_mfma_f32_16x16x32_bf16(a, b, c, 0, 0, 0)

#if __has_builtin(__builtin_amdgcn_exp2f)
#define EXP2F(x) __builtin_amdgcn_exp2f(x)
#else
#define EXP2F(x) exp2f(x)
#endif

// async global->LDS, 16B per lane; LDS dest = wave-uniform base + lane*16
#define GLL16(gp, lp) __builtin_amdgcn_global_load_lds(                                  \
    (__attribute__((address_space(1))) unsigned int*)(unsigned long long)(const void*)(gp), \
    (__attribute__((address_space(3))) unsigned int*)(lp), 16, 0, 0)

// fp32 -> bf16 RNE
__device__ __forceinline__ unsigned short f2b(float f) {
    union { float f; unsigned int u; } v;
    v.f = f;
    unsigned int u = v.u;
    return (unsigned short)((u + 0x7fffu + ((u >> 16) & 1u)) >> 16);
}

static __device__ __forceinline__ f32x4 max4(f32x4 x, f32x4 y) {
    f32x4 r;
    r[0] = fmaxf(x[0], y[0]); r[1] = fmaxf(x[1], y[1]);
    r[2] = fmaxf(x[2], y[2]); r[3] = fmaxf(x[3], y[3]);
    return r;
}

// ---------------- merged cvt: x (+mask) and 4 weights ----------------
__global__ void cvt_all(const float* __restrict__ x,
                        const float* __restrict__ w0, const float* __restrict__ w1,
                        const float* __restrict__ w2, const float* __restrict__ w3,
                        unsigned short* __restrict__ xb, unsigned short* __restrict__ wb,
                        float* __restrict__ maskbuf) {
    int blk = blockIdx.x;
    if (blk < 4096) {
        int i = blk * 256 + threadIdx.x;           // 0..1048575 float4s
        float4 v = ((const float4*)x)[i];
        ushort4 o;
        o.x = f2b(v.x); o.y = f2b(v.y); o.z = f2b(v.z); o.w = f2b(v.w);
        ((ushort4*)xb)[i] = o;
        if ((i & 255) == 0)
            maskbuf[i >> 8] = (v.x != 0.0f) ? 0.0f : -1e30f;
    } else {
        int wi = blk - 4096;
        int widx = wi >> 10;
        int i = (wi & 1023) * 256 + threadIdx.x;   // 0..262143 float4s
        const float* src = widx == 0 ? w0 : (widx == 1 ? w1 : (widx == 2 ? w2 : w3));
        float4 v = ((const float4*)src)[i];
        ushort4 o;
        o.x = f2b(v.x); o.y = f2b(v.y); o.z = f2b(v.z); o.w = f2b(v.w);
        ((ushort4*)(wb + ((size_t)widx << 20)))[i] = o;
    }
}

// fold softmax scale (Dh^-0.5) and log2(e) into Q so attn uses raw exp2
#define QSCALE (0.125f * 1.44269504088896341f)

// ---------------- fused QKV GEMM, double-buffered, 1 barrier/iter ----------------
// grid (24, 32): blockIdx.x>>3 = seg (0=Q,1=K,2=V). Q,K out: (B,H,T,64) bf16
// (Q pre-scaled). V out: (B,H,64,Tperm), pos = q*8 + t*4 + i for key 16t+4q+i
// within each 32-key group (one b128 = MFMA32 A-frag in attn).
__global__ __launch_bounds__(256) void gemm_qkv(
        const unsigned short* __restrict__ A,
        const unsigned short* __restrict__ wq, const unsigned short* __restrict__ wk,
        const unsigned short* __restrict__ wv,
        const float* __restrict__ bq, const float* __restrict__ bk,
        const float* __restrict__ bv,
        unsigned short* __restrict__ qbuf, unsigned short* __restrict__ kbuf,
        unsigned short* __restrict__ vbuf) {
    __shared__ __attribute__((aligned(16))) unsigned short As[2][128 * 32];
    __shared__ __attribute__((aligned(16))) unsigned short Bs[2][128 * 32];
    int tid = threadIdx.x;
    int lane = tid & 63, wave = tid >> 6;
    int lane15 = lane & 15, quad = lane >> 4;
    int seg = blockIdx.x >> 3;
    int bn = (blockIdx.x & 7) * 128;
    int bm = blockIdx.y * 128;
    const unsigned short* Bw = seg == 0 ? wq : (seg == 1 ? wk : wv);
    const float* bias = seg == 0 ? bq : (seg == 1 ? bk : bv);
    int wm = (wave >> 1) * 64, wn = (wave & 1) * 64;

    f32x4 acc[4][4];
#pragma unroll
    for (int i = 0; i < 4; i++)
#pragma unroll
        for (int j = 0; j < 4; j++) acc[i][j] = (f32x4){0.f, 0.f, 0.f, 0.f};

    int arow = tid >> 2, acol = (tid & 3) * 8;
    const unsigned short* A0 = &A[(size_t)(bm + arow) * 1024 + acol];
    const unsigned short* A1 = A0 + (size_t)64 * 1024;
    const unsigned short* B0 = &Bw[(size_t)(bn + arow) * 1024 + acol];
    const unsigned short* B1 = B0 + (size_t)64 * 1024;

    // prologue: stage k-tile 0 into buffer 0
    GLL16(A0, &As[0][(size_t)tid * 8]);
    GLL16(A1, &As[0][(size_t)(tid + 256) * 8]);
    GLL16(B0, &Bs[0][(size_t)tid * 8]);
    GLL16(B1, &Bs[0][(size_t)(tid + 256) * 8]);

    for (int it = 0; it < 32; it++) {
        int cur = it & 1;
        __syncthreads();                 // tile[cur] ready; prior reads drained
        if (it < 31) {                   // prefetch tile[cur^1]
            int kn = (it + 1) * 32;
            GLL16(A0 + kn, &As[cur ^ 1][(size_t)tid * 8]);
            GLL16(A1 + kn, &As[cur ^ 1][(size_t)(tid + 256) * 8]);
            GLL16(B0 + kn, &Bs[cur ^ 1][(size_t)tid * 8]);
            GLL16(B1 + kn, &Bs[cur ^ 1][(size_t)(tid + 256) * 8]);
        }
        const unsigned short* as = As[cur];
        const unsigned short* bs = Bs[cur];
        short8 af[4], bf[4];
#pragma unroll
        for (int i = 0; i < 4; i++)
            af[i] = *(const short8*)&as[(wm + i * 16 + lane15) * 32 + quad * 8];
#pragma unroll
        for (int j = 0; j < 4; j++)
            bf[j] = *(const short8*)&bs[(wn + j * 16 + lane15) * 32 + quad * 8];
#pragma unroll
        for (int i = 0; i < 4; i++)
#pragma unroll
            for (int j = 0; j < 4; j++)
                acc[i][j] = MFMA32(af[i], bf[j], acc[i][j]);
    }

    int bb = bm >> 11;
#pragma unroll
    for (int j = 0; j < 4; j++) {
        int nl = bn + wn + j * 16 + lane15;     // 0..1023
        int h = nl >> 6, d = nl & 63;
        float bv_ = bias[nl];
        if (seg == 2) {
            size_t vbase = ((size_t)((bb * 16 + h) * 64 + d)) * 2048;
#pragma unroll
            for (int i = 0; i < 4; i++) {
                int tk0 = (bm & 2047) + wm + i * 16 + quad * 4;
                int grp = tk0 >> 5;
                ushort4 pk;
                pk.x = f2b(acc[i][j][0] + bv_);
                pk.y = f2b(acc[i][j][1] + bv_);
                pk.z = f2b(acc[i][j][2] + bv_);
                pk.w = f2b(acc[i][j][3] + bv_);
                *(ushort4*)&vbuf[vbase + grp * 32 + quad * 8 + (i & 1) * 4] = pk;
            }
        } else {
#pragma unroll
            for (int i = 0; i < 4; i++)
#pragma unroll
                for (int r = 0; r < 4; r++) {
                    int m = bm + wm + i * 16 + quad * 4 + r;
                    int tk = m & 2047;
                    float v = acc[i][j][r] + bv_;
                    size_t off = ((size_t)((bb * 16 + h) * 2048 + tk)) * 64 + d;
                    if (seg == 0) qbuf[off] = f2b(v * QSCALE);
                    else          kbuf[off] = f2b(v);
                }
        }
    }
}

// ---------------- output projection GEMM: 64x128 tiles, dbuf, fp32 out ----------------
// grid (8, 64) = 512 blocks (2/CU). Wave tile 32x64.
__global__ __launch_bounds__(256) void gemm_proj(
        const unsigned short* __restrict__ A, const unsigned short* __restrict__ Bw,
        const float* __restrict__ bias, float* __restrict__ out) {
    __shared__ __attribute__((aligned(16))) unsigned short As[2][64 * 32];
    __shared__ __attribute__((aligned(16))) unsigned short Bs[2][128 * 32];
    int tid = threadIdx.x;
    int lane = tid & 63, wave = tid >> 6;
    int lane15 = lane & 15, quad = lane >> 4;
    int bn = blockIdx.x * 128, bm = blockIdx.y * 64;
    int wm = (wave >> 1) * 32, wn = (wave & 1) * 64;

    f32x4 acc[2][4];
#pragma unroll
    for (int i = 0; i < 2; i++)
#pragma unroll
        for (int j = 0; j < 4; j++) acc[i][j] = (f32x4){0.f, 0.f, 0.f, 0.f};

    int arow = tid >> 2, acol = (tid & 3) * 8;
    const unsigned short* A0 = &A[(size_t)(bm + arow) * 1024 + acol];
    const unsigned short* B0 = &Bw[(size_t)(bn + arow) * 1024 + acol];
    const unsigned short* B1 = B0 + (size_t)64 * 1024;

    GLL16(A0, &As[0][(size_t)tid * 8]);
    GLL16(B0, &Bs[0][(size_t)tid * 8]);
    GLL16(B1, &Bs[0][(size_t)(tid + 256) * 8]);

    for (int it = 0; it < 32; it++) {
        int cur = it & 1;
        __syncthreads();
        if (it < 31) {
            int kn = (it + 1) * 32;
            GLL16(A0 + kn, &As[cur ^ 1][(size_t)tid * 8]);
            GLL16(B0 + kn, &Bs[cur ^ 1][(size_t)tid * 8]);
            GLL16(B1 + kn, &Bs[cur ^ 1][(size_t)(tid + 256) * 8]);
        }
        const unsigned short* as = As[cur];
        const unsigned short* bs = Bs[cur];
        short8 af[2], bf[4];
#pragma unroll
        for (int i = 0; i < 2; i++)
            af[i] = *(const short8*)&as[(wm + i * 16 + lane15) * 32 + quad * 8];
#pragma unroll
        for (int j = 0; j < 4; j++)
            bf[j] = *(const short8*)&bs[(wn + j * 16 + lane15) * 32 + quad * 8];
#pragma unroll
        for (int i = 0; i < 2; i++)
#pragma unroll
            for (int j = 0; j < 4; j++)
                acc[i][j] = MFMA32(af[i], bf[j], acc[i][j]);
    }

#pragma unroll
    for (int j = 0; j < 4; j++) {
        int n = bn + wn + j * 16 + lane15;
        float bv_ = bias[n];
#pragma unroll
        for (int i = 0; i < 2; i++)
#pragma unroll
            for (int r = 0; r < 4; r++) {
                int m = bm + wm + i * 16 + quad * 4 + r;
                out[(size_t)m * 1024 + n] = acc[i][j][r] + bv_;
            }
    }
}

// ---------------- flash attention v5: zero-LDS, zero-barrier, L2-direct ----------------
// K+V per (b,h) combo = 512 KB; XCD-swizzled blockIdx pins 4 combos (2 MB) per
// 4 MB XCD-L2, so K/V reads are L2 hits — LDS staging was pure overhead
// (and its __syncthreads drained vmcnt every iter, lockstepping all 4 waves).
// Now each wave free-runs: no barriers, loads straight from L2, V loads issued
// before softmax so ~500 cy of exp2/pack hides their latency. s_setprio(1)
// around MFMA clusters (applicable now that waves are at independent phases).
// S^T C-layout (col=query=lane15, row=key) + permuted V order means the exp'd
// scores of two 16-key tiles concatenate into the exact 16x16x32 B-operand
// fragment for PV — zero-movement P, PV in MFMA32.
__global__ __launch_bounds__(256, 2) void attn_kernel(
        const unsigned short* __restrict__ qbuf, const unsigned short* __restrict__ kbuf,
        const unsigned short* __restrict__ vtbuf, const float* __restrict__ maskbuf,
        unsigned short* __restrict__ attnout) {
    int id = blockIdx.x;
    int combo = (id & 7) | (((id >> 7) & 3) << 3);   // same (b,h) stays on one XCD
    int qt = (id >> 3) & 15;
    int b = combo >> 4, h = combo & 15;
    int tid = threadIdx.x, lane = tid & 63, wave = tid >> 6;
    int lane15 = lane & 15, quad = lane >> 4;
    int q0 = qt * 128 + wave * 32;

    const unsigned short* Q  = qbuf  + (size_t)combo * 2048 * 64;
    const unsigned short* Kp = kbuf  + (size_t)combo * 2048 * 64;
    const unsigned short* Vt = vtbuf + (size_t)combo * 64 * 2048;
    const float* mb = maskbuf + b * 2048;

    // Q as 16x16x32 B-operand: B[n=lane15][k=quad*8+j]; two 16-q tiles, two k-halves
    short8 qf[2][2];
#pragma unroll
    for (int a = 0; a < 2; a++)
#pragma unroll
        for (int g = 0; g < 2; g++)
            qf[a][g] = *(const short8*)&Q[(size_t)(q0 + a * 16 + lane15) * 64 + g * 32 + quad * 8];

    float m_run[2] = {-1e30f, -1e30f}, l_run[2] = {0.f, 0.f};
    f32x4 o[2][4];
#pragma unroll
    for (int a = 0; a < 2; a++)
#pragma unroll
        for (int c = 0; c < 4; c++) o[a][c] = (f32x4){0.f, 0.f, 0.f, 0.f};

    const f32x4 z4 = {0.f, 0.f, 0.f, 0.f};

    // loop-invariant lane bases
    const unsigned short* Krow = &Kp[(size_t)lane15 * 64 + quad * 8];              // + (kb+t*16)*64
    const unsigned short* Vrow = &Vt[(size_t)lane15 * 2048 + quad * 8];            // + c*16*2048 + kb + g*32

    for (int it = 0; it < 16; it++) {
        int kb = it * 128;

        // ---- K fragments for 8 key-tiles, straight from L2 ----
        short8 k0[8], k1[8];
#pragma unroll
        for (int t = 0; t < 8; t++) {
            const unsigned short* kr = Krow + (size_t)(kb + t * 16) * 64;
            k0[t] = *(const short8*)kr;
            k1[t] = *(const short8*)(kr + 32);
        }

        // ---- S^T = K.Q^T : 8 key-tiles x 2 q-tiles ----
        f32x4 s[2][8];
        __builtin_amdgcn_s_setprio(1);
#pragma unroll
        for (int t = 0; t < 8; t++) {
            f32x4 t0 = MFMA32(k0[t], qf[0][0], z4);
            s[0][t] = MFMA32(k1[t], qf[0][1], t0);
            f32x4 t1 = MFMA32(k0[t], qf[1][0], z4);
            s[1][t] = MFMA32(k1[t], qf[1][1], t1);
        }
        __builtin_amdgcn_s_setprio(0);

        // ---- issue V loads now; softmax below hides their L2 latency ----
        short8 vf[4][4];
#pragma unroll
        for (int c = 0; c < 4; c++)
#pragma unroll
            for (int g = 0; g < 4; g++)
                vf[c][g] = *(const short8*)(Vrow + (size_t)c * 16 * 2048 + kb + g * 32);

        // ---- mask (additive -1e30; scores already in log2 domain) ----
#pragma unroll
        for (int t = 0; t < 8; t++) {
            f32x4 mkt = *(const f32x4*)&mb[kb + t * 16 + quad * 4];
            s[0][t] += mkt;
            s[1][t] += mkt;
        }

        // ---- online softmax + pack P into MFMA32 B-frags ----
        short8 pb8[2][4];
#pragma unroll
        for (int a = 0; a < 2; a++) {
            f32x4 m4 = s[a][0];
#pragma unroll
            for (int t = 1; t < 8; t++) m4 = max4(m4, s[a][t]);
            float mx = fmaxf(fmaxf(m4[0], m4[1]), fmaxf(m4[2], m4[3]));
            mx = fmaxf(mx, __shfl_xor(mx, 16));
            mx = fmaxf(mx, __shfl_xor(mx, 32));
            float mnew = fmaxf(m_run[a], mx);
            float alpha = EXP2F(m_run[a] - mnew);
            m_run[a] = mnew;
            float ls = 0.f;
#pragma unroll
            for (int g = 0; g < 4; g++) {
                float e0 = EXP2F(s[a][2 * g][0] - mnew);
                float e1 = EXP2F(s[a][2 * g][1] - mnew);
                float e2 = EXP2F(s[a][2 * g][2] - mnew);
                float e3 = EXP2F(s[a][2 * g][3] - mnew);
                float f0 = EXP2F(s[a][2 * g + 1][0] - mnew);
                float f1 = EXP2F(s[a][2 * g + 1][1] - mnew);
                float f2 = EXP2F(s[a][2 * g + 1][2] - mnew);
                float f3 = EXP2F(s[a][2 * g + 1][3] - mnew);
                ls += ((e0 + e1) + (e2 + e3)) + ((f0 + f1) + (f2 + f3));
                union { uint4 u; short8 sv; } pu;   // bf16 truncation pack (P in [0,1])
                pu.u.x = __builtin_amdgcn_perm(__float_as_uint(e1), __float_as_uint(e0), 0x07060302u);
                pu.u.y = __builtin_amdgcn_perm(__float_as_uint(e3), __float_as_uint(e2), 0x07060302u);
                pu.u.z = __builtin_amdgcn_perm(__float_as_uint(f1), __float_as_uint(f0), 0x07060302u);
                pu.u.w = __builtin_amdgcn_perm(__float_as_uint(f3), __float_as_uint(f2), 0x07060302u);
                pb8[a][g] = pu.sv;
            }
            l_run[a] = l_run[a] * alpha + ls;
#pragma unroll
            for (int c = 0; c < 4; c++) o[a][c] *= alpha;
        }

        // ---- O^T += V^T.P^T : MFMA32, A-frag shared by both q-tiles ----
        __builtin_amdgcn_s_setprio(1);
#pragma unroll
        for (int c = 0; c < 4; c++)
#pragma unroll
            for (int g = 0; g < 4; g++) {
                o[0][c] = MFMA32(vf[c][g], pb8[0][g], o[0][c]);
                o[1][c] = MFMA32(vf[c][g], pb8[1][g], o[1][c]);
            }
        __builtin_amdgcn_s_setprio(0);
    }

    // ---- epilogue ----
#pragma unroll
    for (int a = 0; a < 2; a++) {
        float l = l_run[a];
        l += __shfl_xor(l, 16);
        l += __shfl_xor(l, 32);
        float rl = 1.0f / l;
        size_t row = (size_t)(b * 2048 + q0 + a * 16 + lane15) * 1024 + h * 64 + quad * 4;
#pragma unroll
        for (int c = 0; c < 4; c++) {
            ushort4 pk;
            pk.x = f2b(o[a][c][0] * rl);
            pk.y = f2b(o[a][c][1] * rl);
            pk.z = f2b(o[a][c][2] * rl);
            pk.w = f2b(o[a][c][3] * rl);
            *(ushort4*)&attnout[row + c * 16] = pk;
        }
    }
}

extern "C" void kernel_launch(void* const* d_in, const int* in_sizes, int n_in,
                              void* d_out, int out_size, void* d_ws, size_t ws_size,
                              hipStream_t stream) {
    const float* x    = (const float*)d_in[0];
    const float* wq_w = (const float*)d_in[1];
    const float* wq_b = (const float*)d_in[2];
    const float* wk_w = (const float*)d_in[3];
    const float* wk_b = (const float*)d_in[4];
    const float* wv_w = (const float*)d_in[5];
    const float* wv_b = (const float*)d_in[6];
    const float* wo_w = (const float*)d_in[7];
    const float* wo_b = (const float*)d_in[8];
    float* out = (float*)d_out;

    char* ws = (char*)d_ws;
    size_t off = 0;
    unsigned short* xb      = (unsigned short*)(ws + off); off += (size_t)4096 * 1024 * 2;
    unsigned short* wb      = (unsigned short*)(ws + off); off += (size_t)4 * 1024 * 1024 * 2;
    unsigned short* qbuf    = (unsigned short*)(ws + off); off += (size_t)4096 * 1024 * 2;
    unsigned short* kbuf    = (unsigned short*)(ws + off); off += (size_t)4096 * 1024 * 2;
    unsigned short* vbuf    = (unsigned short*)(ws + off); off += (size_t)4096 * 1024 * 2;
    unsigned short* attnout = (unsigned short*)(ws + off); off += (size_t)4096 * 1024 * 2;
    float* maskbuf          = (float*)(ws + off);          off += 4096 * 4;

    unsigned short* wqb = wb;
    unsigned short* wkb = wb + (1u << 20);
    unsigned short* wvb = wb + (2u << 20);
    unsigned short* wob = wb + (3u << 20);

    cvt_all<<<8192, 256, 0, stream>>>(x, wq_w, wk_w, wv_w, wo_w, xb, wb, maskbuf);

    gemm_qkv<<<dim3(24, 32), 256, 0, stream>>>(xb, wqb, wkb, wvb,
                                               wq_b, wk_b, wv_b, qbuf, kbuf, vbuf);

    attn_kernel<<<512, 256, 0, stream>>>(qbuf, kbuf, vbuf, maskbuf, attnout);

    gemm_proj<<<dim3(8, 64), 256, 0, stream>>>(attnout, wob, wo_b, out);
}

// Round 2
// 213.652 us; speedup vs baseline: 1.2782x; 1.2782x over previous
//
#include <hip/hip_runtime.h>
#include <hip/hip_bf16.h>

typedef short short8 __attribute__((ext_vector_type(8)));
typedef float f32x4 __attribute__((ext_vector_type(4)));

#define MFMA32(a, b, c) __builtin_amdgcn_mfma_f32_16x16x32_bf16(a, b, c, 0, 0, 0)

#if __has_builtin(__builtin_amdgcn_exp2f)
#define EXP2F(x) __builtin_amdgcn_exp2f(x)
#else
#define EXP2F(x) exp2f(x)
#endif

// async global->LDS, 16B per lane; LDS dest = wave-uniform base + lane*16
#define GLL16(gp, lp) __builtin_amdgcn_global_load_lds(                                  \
    (__attribute__((address_space(1))) unsigned int*)(unsigned long long)(const void*)(gp), \
    (__attribute__((address_space(3))) unsigned int*)(lp), 16, 0, 0)

// fp32 -> bf16 RNE
__device__ __forceinline__ unsigned short f2b(float f) {
    union { float f; unsigned int u; } v;
    v.f = f;
    unsigned int u = v.u;
    return (unsigned short)((u + 0x7fffu + ((u >> 16) & 1u)) >> 16);
}

static __device__ __forceinline__ f32x4 max4(f32x4 x, f32x4 y) {
    f32x4 r;
    r[0] = fmaxf(x[0], y[0]); r[1] = fmaxf(x[1], y[1]);
    r[2] = fmaxf(x[2], y[2]); r[3] = fmaxf(x[3], y[3]);
    return r;
}

// ---------------- merged cvt: x (+mask) and 4 weights ----------------
__global__ void cvt_all(const float* __restrict__ x,
                        const float* __restrict__ w0, const float* __restrict__ w1,
                        const float* __restrict__ w2, const float* __restrict__ w3,
                        unsigned short* __restrict__ xb, unsigned short* __restrict__ wb,
                        float* __restrict__ maskbuf) {
    int blk = blockIdx.x;
    if (blk < 4096) {
        int i = blk * 256 + threadIdx.x;           // 0..1048575 float4s
        float4 v = ((const float4*)x)[i];
        ushort4 o;
        o.x = f2b(v.x); o.y = f2b(v.y); o.z = f2b(v.z); o.w = f2b(v.w);
        ((ushort4*)xb)[i] = o;
        if ((i & 255) == 0)
            maskbuf[i >> 8] = (v.x != 0.0f) ? 0.0f : -1e30f;
    } else {
        int wi = blk - 4096;
        int widx = wi >> 10;
        int i = (wi & 1023) * 256 + threadIdx.x;   // 0..262143 float4s
        const float* src = widx == 0 ? w0 : (widx == 1 ? w1 : (widx == 2 ? w2 : w3));
        float4 v = ((const float4*)src)[i];
        ushort4 o;
        o.x = f2b(v.x); o.y = f2b(v.y); o.z = f2b(v.z); o.w = f2b(v.w);
        ((ushort4*)(wb + ((size_t)widx << 20)))[i] = o;
    }
}

// fold softmax scale (Dh^-0.5) and log2(e) into Q so attn uses raw exp2
#define QSCALE (0.125f * 1.44269504088896341f)

// ---------------- fused QKV GEMM, double-buffered, 1 barrier/iter ----------------
// grid (24, 32): blockIdx.x>>3 = seg (0=Q,1=K,2=V). Q,K out: (B,H,T,64) bf16
// (Q pre-scaled). V out: (B,H,64,Tperm), pos = q*8 + t*4 + i for key 16t+4q+i
// within each 32-key group (one b128 = MFMA32 A-frag in attn).
__global__ __launch_bounds__(256) void gemm_qkv(
        const unsigned short* __restrict__ A,
        const unsigned short* __restrict__ wq, const unsigned short* __restrict__ wk,
        const unsigned short* __restrict__ wv,
        const float* __restrict__ bq, const float* __restrict__ bk,
        const float* __restrict__ bv,
        unsigned short* __restrict__ qbuf, unsigned short* __restrict__ kbuf,
        unsigned short* __restrict__ vbuf) {
    __shared__ __attribute__((aligned(16))) unsigned short As[2][128 * 32];
    __shared__ __attribute__((aligned(16))) unsigned short Bs[2][128 * 32];
    int tid = threadIdx.x;
    int lane = tid & 63, wave = tid >> 6;
    int lane15 = lane & 15, quad = lane >> 4;
    int seg = blockIdx.x >> 3;
    int bn = (blockIdx.x & 7) * 128;
    int bm = blockIdx.y * 128;
    const unsigned short* Bw = seg == 0 ? wq : (seg == 1 ? wk : wv);
    const float* bias = seg == 0 ? bq : (seg == 1 ? bk : bv);
    int wm = (wave >> 1) * 64, wn = (wave & 1) * 64;

    f32x4 acc[4][4];
#pragma unroll
    for (int i = 0; i < 4; i++)
#pragma unroll
        for (int j = 0; j < 4; j++) acc[i][j] = (f32x4){0.f, 0.f, 0.f, 0.f};

    int arow = tid >> 2, acol = (tid & 3) * 8;
    const unsigned short* A0 = &A[(size_t)(bm + arow) * 1024 + acol];
    const unsigned short* A1 = A0 + (size_t)64 * 1024;
    const unsigned short* B0 = &Bw[(size_t)(bn + arow) * 1024 + acol];
    const unsigned short* B1 = B0 + (size_t)64 * 1024;

    // prologue: stage k-tile 0 into buffer 0
    GLL16(A0, &As[0][(size_t)tid * 8]);
    GLL16(A1, &As[0][(size_t)(tid + 256) * 8]);
    GLL16(B0, &Bs[0][(size_t)tid * 8]);
    GLL16(B1, &Bs[0][(size_t)(tid + 256) * 8]);

    for (int it = 0; it < 32; it++) {
        int cur = it & 1;
        __syncthreads();                 // tile[cur] ready; prior reads drained
        if (it < 31) {                   // prefetch tile[cur^1]
            int kn = (it + 1) * 32;
            GLL16(A0 + kn, &As[cur ^ 1][(size_t)tid * 8]);
            GLL16(A1 + kn, &As[cur ^ 1][(size_t)(tid + 256) * 8]);
            GLL16(B0 + kn, &Bs[cur ^ 1][(size_t)tid * 8]);
            GLL16(B1 + kn, &Bs[cur ^ 1][(size_t)(tid + 256) * 8]);
        }
        const unsigned short* as = As[cur];
        const unsigned short* bs = Bs[cur];
        short8 af[4], bf[4];
#pragma unroll
        for (int i = 0; i < 4; i++)
            af[i] = *(const short8*)&as[(wm + i * 16 + lane15) * 32 + quad * 8];
#pragma unroll
        for (int j = 0; j < 4; j++)
            bf[j] = *(const short8*)&bs[(wn + j * 16 + lane15) * 32 + quad * 8];
#pragma unroll
        for (int i = 0; i < 4; i++)
#pragma unroll
            for (int j = 0; j < 4; j++)
                acc[i][j] = MFMA32(af[i], bf[j], acc[i][j]);
    }

    int bb = bm >> 11;
#pragma unroll
    for (int j = 0; j < 4; j++) {
        int nl = bn + wn + j * 16 + lane15;     // 0..1023
        int h = nl >> 6, d = nl & 63;
        float bv_ = bias[nl];
        if (seg == 2) {
            size_t vbase = ((size_t)((bb * 16 + h) * 64 + d)) * 2048;
#pragma unroll
            for (int i = 0; i < 4; i++) {
                int tk0 = (bm & 2047) + wm + i * 16 + quad * 4;
                int grp = tk0 >> 5;
                ushort4 pk;
                pk.x = f2b(acc[i][j][0] + bv_);
                pk.y = f2b(acc[i][j][1] + bv_);
                pk.z = f2b(acc[i][j][2] + bv_);
                pk.w = f2b(acc[i][j][3] + bv_);
                *(ushort4*)&vbuf[vbase + grp * 32 + quad * 8 + (i & 1) * 4] = pk;
            }
        } else {
#pragma unroll
            for (int i = 0; i < 4; i++)
#pragma unroll
                for (int r = 0; r < 4; r++) {
                    int m = bm + wm + i * 16 + quad * 4 + r;
                    int tk = m & 2047;
                    float v = acc[i][j][r] + bv_;
                    size_t off = ((size_t)((bb * 16 + h) * 2048 + tk)) * 64 + d;
                    if (seg == 0) qbuf[off] = f2b(v * QSCALE);
                    else          kbuf[off] = f2b(v);
                }
        }
    }
}

// ---------------- output projection GEMM: 64x128 tiles, dbuf, fp32 out ----------------
// grid (8, 64) = 512 blocks (2/CU). Wave tile 32x64.
__global__ __launch_bounds__(256) void gemm_proj(
        const unsigned short* __restrict__ A, const unsigned short* __restrict__ Bw,
        const float* __restrict__ bias, float* __restrict__ out) {
    __shared__ __attribute__((aligned(16))) unsigned short As[2][64 * 32];
    __shared__ __attribute__((aligned(16))) unsigned short Bs[2][128 * 32];
    int tid = threadIdx.x;
    int lane = tid & 63, wave = tid >> 6;
    int lane15 = lane & 15, quad = lane >> 4;
    int bn = blockIdx.x * 128, bm = blockIdx.y * 64;
    int wm = (wave >> 1) * 32, wn = (wave & 1) * 64;

    f32x4 acc[2][4];
#pragma unroll
    for (int i = 0; i < 2; i++)
#pragma unroll
        for (int j = 0; j < 4; j++) acc[i][j] = (f32x4){0.f, 0.f, 0.f, 0.f};

    int arow = tid >> 2, acol = (tid & 3) * 8;
    const unsigned short* A0 = &A[(size_t)(bm + arow) * 1024 + acol];
    const unsigned short* B0 = &Bw[(size_t)(bn + arow) * 1024 + acol];
    const unsigned short* B1 = B0 + (size_t)64 * 1024;

    GLL16(A0, &As[0][(size_t)tid * 8]);
    GLL16(B0, &Bs[0][(size_t)tid * 8]);
    GLL16(B1, &Bs[0][(size_t)(tid + 256) * 8]);

    for (int it = 0; it < 32; it++) {
        int cur = it & 1;
        __syncthreads();
        if (it < 31) {
            int kn = (it + 1) * 32;
            GLL16(A0 + kn, &As[cur ^ 1][(size_t)tid * 8]);
            GLL16(B0 + kn, &Bs[cur ^ 1][(size_t)tid * 8]);
            GLL16(B1 + kn, &Bs[cur ^ 1][(size_t)(tid + 256) * 8]);
        }
        const unsigned short* as = As[cur];
        const unsigned short* bs = Bs[cur];
        short8 af[2], bf[4];
#pragma unroll
        for (int i = 0; i < 2; i++)
            af[i] = *(const short8*)&as[(wm + i * 16 + lane15) * 32 + quad * 8];
#pragma unroll
        for (int j = 0; j < 4; j++)
            bf[j] = *(const short8*)&bs[(wn + j * 16 + lane15) * 32 + quad * 8];
#pragma unroll
        for (int i = 0; i < 2; i++)
#pragma unroll
            for (int j = 0; j < 4; j++)
                acc[i][j] = MFMA32(af[i], bf[j], acc[i][j]);
    }

#pragma unroll
    for (int j = 0; j < 4; j++) {
        int n = bn + wn + j * 16 + lane15;
        float bv_ = bias[n];
#pragma unroll
        for (int i = 0; i < 2; i++)
#pragma unroll
            for (int r = 0; r < 4; r++) {
                int m = bm + wm + i * 16 + quad * 4 + r;
                out[(size_t)m * 1024 + n] = acc[i][j][r] + bv_;
            }
    }
}

// ---------------- flash attention v6: v4 LDS/dbuf structure, 8 waves x 16q ----------------
// Same decomposition as v4 (512 blocks, 128 queries/block, K/V double-buffered
// in LDS, 1 barrier/iter) but 512 threads = 8 waves of 16 queries each instead
// of 4 waves of 32. Occupancy: 2 blocks/CU x 8 waves = 16 waves/CU = 4/SIMD
// (was 2/SIMD) — v4 was latency-bound (per-iter 12.4k cyc vs ~4k cyc of busy
// resources), so doubling resident waves compresses the dependency-stall gap.
// __launch_bounds__(512,4) caps VGPR at 128; per-wave state is halved (~100).
// S^T C-layout (col=query=lane15, row=key) + permuted V order means the exp'd
// scores of two 16-key tiles concatenate into the exact 16x16x32 B-operand
// fragment for PV — zero-movement P, PV in MFMA32.
__global__ __launch_bounds__(512, 4) void attn_kernel(
        const unsigned short* __restrict__ qbuf, const unsigned short* __restrict__ kbuf,
        const unsigned short* __restrict__ vtbuf, const float* __restrict__ maskbuf,
        unsigned short* __restrict__ attnout) {
    __shared__ __attribute__((aligned(16))) unsigned short Ks[2][128 * 64];
    __shared__ __attribute__((aligned(16))) unsigned short Vs[2][64 * 128];

    int id = blockIdx.x;
    int combo = (id & 7) | (((id >> 7) & 3) << 3);   // same (b,h) stays on one XCD
    int qt = (id >> 3) & 15;
    int b = combo >> 4, h = combo & 15;
    int tid = threadIdx.x, lane = tid & 63, wave = tid >> 6;   // wave 0..7
    int lane15 = lane & 15, quad = lane >> 4;
    int q0 = qt * 128 + wave * 16;

    const unsigned short* Q  = qbuf  + (size_t)combo * 2048 * 64;
    const unsigned short* Kp = kbuf  + (size_t)combo * 2048 * 64;
    const unsigned short* Vt = vtbuf + (size_t)combo * 64 * 2048;
    const float* mb = maskbuf + b * 2048;

    // Q as 16x16x32 B-operand: B[n=lane15][k=quad*8+j]; one 16-q tile, two k-halves
    short8 qf[2];
#pragma unroll
    for (int g = 0; g < 2; g++)
        qf[g] = *(const short8*)&Q[(size_t)(q0 + lane15) * 64 + g * 32 + quad * 8];

    float m_run = -1e30f, l_run = 0.f;
    f32x4 o[4];
#pragma unroll
    for (int c = 0; c < 4; c++) o[c] = (f32x4){0.f, 0.f, 0.f, 0.f};

    const f32x4 z4 = {0.f, 0.f, 0.f, 0.f};
    int x7 = lane15 & 7;
    int ci0 = tid;

    // prologue: stage K/V tile 0 into buffer 0 (1024 chunk-slots, 2 rounds of 512)
#pragma unroll
    for (int r2 = 0; r2 < 2; r2++) {
        int ci = ci0 + r2 * 512;
        int kr = ci >> 3, kc = (ci & 7) ^ (kr & 7);
        GLL16(&Kp[(size_t)kr * 64 + kc * 8], &Ks[0][(size_t)ci * 8]);
        int vd = ci >> 4, vc = (ci & 15) ^ (vd & 15);
        GLL16(&Vt[(size_t)vd * 2048 + vc * 8], &Vs[0][(size_t)ci * 8]);
    }

    for (int it = 0; it < 16; it++) {
        int cur = it & 1;
        int kb = it * 128;
        __syncthreads();                       // tile[cur] ready; prior reads drained
        if (it < 15) {                         // prefetch tile[cur^1]
            int kn = kb + 128;
#pragma unroll
            for (int r2 = 0; r2 < 2; r2++) {
                int ci = ci0 + r2 * 512;
                int kr = ci >> 3, kc = (ci & 7) ^ (kr & 7);
                GLL16(&Kp[(size_t)(kn + kr) * 64 + kc * 8], &Ks[cur ^ 1][(size_t)ci * 8]);
                int vd = ci >> 4, vc = (ci & 15) ^ (vd & 15);
                GLL16(&Vt[(size_t)vd * 2048 + kn + vc * 8], &Vs[cur ^ 1][(size_t)ci * 8]);
            }
        }
        const unsigned short* ks = Ks[cur];
        const unsigned short* vs = Vs[cur];

        // ---- S^T = K.Q^T : 8 key-tiles x 1 q-tile ----
        f32x4 s[8];
#pragma unroll
        for (int t = 0; t < 8; t++) {
            int row = t * 16 + lane15;
            short8 k0 = *(const short8*)&ks[row * 64 + (quad ^ x7) * 8];
            short8 k1 = *(const short8*)&ks[row * 64 + ((quad + 4) ^ x7) * 8];
            f32x4 t0 = MFMA32(k0, qf[0], z4);
            s[t] = MFMA32(k1, qf[1], t0);
        }
        // ---- mask (additive -1e30; scores already in log2 domain) ----
#pragma unroll
        for (int t = 0; t < 8; t++)
            s[t] += *(const f32x4*)&mb[kb + t * 16 + quad * 4];

        // ---- online softmax + pack P into MFMA32 B-frags ----
        f32x4 m4 = s[0];
#pragma unroll
        for (int t = 1; t < 8; t++) m4 = max4(m4, s[t]);
        float mx = fmaxf(fmaxf(m4[0], m4[1]), fmaxf(m4[2], m4[3]));
        mx = fmaxf(mx, __shfl_xor(mx, 16));
        mx = fmaxf(mx, __shfl_xor(mx, 32));
        float mnew = fmaxf(m_run, mx);
        float alpha = EXP2F(m_run - mnew);
        m_run = mnew;
        float ls = 0.f;
        short8 pb8[4];
#pragma unroll
        for (int g = 0; g < 4; g++) {
            float e0 = EXP2F(s[2 * g][0] - mnew);
            float e1 = EXP2F(s[2 * g][1] - mnew);
            float e2 = EXP2F(s[2 * g][2] - mnew);
            float e3 = EXP2F(s[2 * g][3] - mnew);
            float f0 = EXP2F(s[2 * g + 1][0] - mnew);
            float f1 = EXP2F(s[2 * g + 1][1] - mnew);
            float f2 = EXP2F(s[2 * g + 1][2] - mnew);
            float f3 = EXP2F(s[2 * g + 1][3] - mnew);
            ls += ((e0 + e1) + (e2 + e3)) + ((f0 + f1) + (f2 + f3));
            union { uint4 u; short8 sv; } pu;   // bf16 truncation pack (P in [0,1])
            pu.u.x = __builtin_amdgcn_perm(__float_as_uint(e1), __float_as_uint(e0), 0x07060302u);
            pu.u.y = __builtin_amdgcn_perm(__float_as_uint(e3), __float_as_uint(e2), 0x07060302u);
            pu.u.z = __builtin_amdgcn_perm(__float_as_uint(f1), __float_as_uint(f0), 0x07060302u);
            pu.u.w = __builtin_amdgcn_perm(__float_as_uint(f3), __float_as_uint(f2), 0x07060302u);
            pb8[g] = pu.sv;
        }
        l_run = l_run * alpha + ls;
#pragma unroll
        for (int c = 0; c < 4; c++) o[c] *= alpha;

        // ---- O^T += V^T.P^T : MFMA32, A-frag = one b128 ----
#pragma unroll
        for (int c = 0; c < 4; c++) {
            int d = c * 16 + lane15;
#pragma unroll
            for (int g = 0; g < 4; g++) {
                int skc = (g * 4 + quad) ^ lane15;
                short8 vv = *(const short8*)&vs[d * 128 + skc * 8];
                o[c] = MFMA32(vv, pb8[g], o[c]);
            }
        }
    }

    // ---- epilogue ----
    float l = l_run;
    l += __shfl_xor(l, 16);
    l += __shfl_xor(l, 32);
    float rl = 1.0f / l;
    size_t row = (size_t)(b * 2048 + q0 + lane15) * 1024 + h * 64 + quad * 4;
#pragma unroll
    for (int c = 0; c < 4; c++) {
        ushort4 pk;
        pk.x = f2b(o[c][0] * rl);
        pk.y = f2b(o[c][1] * rl);
        pk.z = f2b(o[c][2] * rl);
        pk.w = f2b(o[c][3] * rl);
        *(ushort4*)&attnout[row + c * 16] = pk;
    }
}

extern "C" void kernel_launch(void* const* d_in, const int* in_sizes, int n_in,
                              void* d_out, int out_size, void* d_ws, size_t ws_size,
                              hipStream_t stream) {
    const float* x    = (const float*)d_in[0];
    const float* wq_w = (const float*)d_in[1];
    const float* wq_b = (const float*)d_in[2];
    const float* wk_w = (const float*)d_in[3];
    const float* wk_b = (const float*)d_in[4];
    const float* wv_w = (const float*)d_in[5];
    const float* wv_b = (const float*)d_in[6];
    const float* wo_w = (const float*)d_in[7];
    const float* wo_b = (const float*)d_in[8];
    float* out = (float*)d_out;

    char* ws = (char*)d_ws;
    size_t off = 0;
    unsigned short* xb      = (unsigned short*)(ws + off); off += (size_t)4096 * 1024 * 2;
    unsigned short* wb      = (unsigned short*)(ws + off); off += (size_t)4 * 1024 * 1024 * 2;
    unsigned short* qbuf    = (unsigned short*)(ws + off); off += (size_t)4096 * 1024 * 2;
    unsigned short* kbuf    = (unsigned short*)(ws + off); off += (size_t)4096 * 1024 * 2;
    unsigned short* vbuf    = (unsigned short*)(ws + off); off += (size_t)4096 * 1024 * 2;
    unsigned short* attnout = (unsigned short*)(ws + off); off += (size_t)4096 * 1024 * 2;
    float* maskbuf          = (float*)(ws + off);          off += 4096 * 4;

    unsigned short* wqb = wb;
    unsigned short* wkb = wb + (1u << 20);
    unsigned short* wvb = wb + (2u << 20);
    unsigned short* wob = wb + (3u << 20);

    cvt_all<<<8192, 256, 0, stream>>>(x, wq_w, wk_w, wv_w, wo_w, xb, wb, maskbuf);

    gemm_qkv<<<dim3(24, 32), 256, 0, stream>>>(xb, wqb, wkb, wvb,
                                               wq_b, wk_b, wv_b, qbuf, kbuf, vbuf);

    attn_kernel<<<512, 512, 0, stream>>>(qbuf, kbuf, vbuf, maskbuf, attnout);

    gemm_proj<<<dim3(8, 64), 256, 0, stream>>>(attnout, wob, wo_b, out);
}